// Round 4
// baseline (279.472 us; speedup 1.0000x reference)
//
#include <hip/hip_runtime.h>

// CRF forward partition, MI355X. B=1024, L=512, T=52.
//
// p-space recurrence: p_new[j] = exp(f[t,j]) * sum_i E[i][j]*p[i],
// E = exp(transitions), constant. One wave per batch; lane j owns tag j.
//
// R4 vs R3: broadcast p through LDS instead of v_readlane->SGPR.
//  - R2/R3 evidence: VGPR=36 (E stuck in AGPRs), SGPR=96 (ps in SGPRs),
//    ~714 cyc/step vs ~240 ideal => per-fmac (SGPR,AGPR) dual-special-operand
//    copies and/or serialized VALU->SGPR readlane writeback.
//  - Now: lane j writes pv to sp[j] (ds_write_b32), all lanes re-read the
//    52-float vector as 13 ds_read_b128 same-address broadcasts (conflict-
//    free). fmac operands: p in VGPR, E wherever (<=1 special source).
//    Single wave per batch => no barriers; compiler orders via lgkmcnt.

#define TT 52   // TAG_SIZE
#define LL 512  // sequence length
#define NS 4    // steps per group; normalize once per group

__device__ __forceinline__ float rl(float x, int lane) {
    return __int_as_float(__builtin_amdgcn_readlane(__float_as_int(x), lane));
}

__global__ void __launch_bounds__(64, 1) crf_fwd(
    const float* __restrict__ feats,   // (B, L, T)
    const int*   __restrict__ mask,    // (B, L)
    const float* __restrict__ trans,   // (T, T)
    float*       __restrict__ out)     // scalar accumulator (pre-zeroed)
{
    __shared__ float sp[64];            // p broadcast buffer (52 used + spill pad)

    const int b = blockIdx.x;
    const int j = threadIdx.x;          // lane = destination tag
    const bool act = (j < TT);
    const int jc = act ? j : 0;         // clamped index for safe loads

    const float* fb = feats + (size_t)b * LL * TT;
    const int*   mb = mask  + (size_t)b * LL;

    // Per-lane transition column: E[i] = exp(trans[i][j]).
    // -1000 entries (START col / END row) become exact 0.
    float E[TT];
#pragma unroll
    for (int i = 0; i < TT; ++i) {
        float e = __expf(trans[i * TT + jc]);
        E[i] = act ? e : 0.0f;
    }

    // t=0 init: part0[j] = feats[b,0,j] + trans[START][j]; normalize by lane 0.
    float part0 = act ? (fb[j] + trans[(TT - 2) * TT + j]) : -1.0e30f;
    float shift = rl(part0, 0);
    float pv = act ? __expf(part0 - shift) : 0.0f;   // lane j holds p[j]
    sp[j] = pv;                          // publish p (lanes >=TT write pad)

    // Prefetch ring (clamped indices => no guard branches, always in-bounds).
    float fpre[NS];
    int   mc[NS];
#pragma unroll
    for (int u = 0; u < NS; ++u) {
        int t = 1 + u;                  // all < LL
        fpre[u] = fb[t * TT + jc];
        mc[u]   = mb[t];
    }

    // Main loop: 127 branch-free groups covering t = 1 .. 508.
    for (int t0 = 1; t0 < LL - NS + 1; t0 += NS) {
        // issue next group's loads first (~4 steps of latency slack)
        float fnx[NS];
        int   mn[NS];
#pragma unroll
        for (int u = 0; u < NS; ++u) {
            int tn = t0 + NS + u;
            int tcl = tn < LL ? tn : (LL - 1);   // clamp (tail overrun harmless)
            fnx[u] = fb[tcl * TT + jc];
            mn[u]  = mb[tcl];
        }

#pragma unroll
        for (int u = 0; u < NS; ++u) {
            float ef = __expf(fpre[u]);
            // broadcast-read p: 13 x ds_read_b128, same address all lanes
            float4 q[13];
#pragma unroll
            for (int r = 0; r < 13; ++r)
                q[r] = *(const float4*)&sp[4 * r];
            // s_j = sum_i E[i][j] * p[i]  (4 independent FMA chains)
            float a0 = 0.f, a1 = 0.f, a2 = 0.f, a3 = 0.f;
#pragma unroll
            for (int r = 0; r < 13; ++r) {
                a0 = fmaf(q[r].x, E[4 * r + 0], a0);
                a1 = fmaf(q[r].y, E[4 * r + 1], a1);
                a2 = fmaf(q[r].z, E[4 * r + 2], a2);
                a3 = fmaf(q[r].w, E[4 * r + 3], a3);
            }
            float pn = ((a0 + a1) + (a2 + a3)) * ef;
            pv = (mc[u] > 0) ? pn : pv;          // branchless mask select
            if (u == NS - 1) {
                // normalize once per group by lane 0 (>0 always); track shift
                float c = rl(pv, 0);
                shift += __logf(c);
                pv *= __builtin_amdgcn_rcpf(c);
            }
            sp[j] = pv;                  // publish for next step
        }
#pragma unroll
        for (int u = 0; u < NS; ++u) { fpre[u] = fnx[u]; mc[u] = mn[u]; }
    }

    // Tail: t = 509, 510, 511 (3 steps, data already in fpre[0..2]).
#pragma unroll
    for (int u = 0; u < 3; ++u) {
        float ef = __expf(fpre[u]);
        float4 q[13];
#pragma unroll
        for (int r = 0; r < 13; ++r)
            q[r] = *(const float4*)&sp[4 * r];
        float a0 = 0.f, a1 = 0.f, a2 = 0.f, a3 = 0.f;
#pragma unroll
        for (int r = 0; r < 13; ++r) {
            a0 = fmaf(q[r].x, E[4 * r + 0], a0);
            a1 = fmaf(q[r].y, E[4 * r + 1], a1);
            a2 = fmaf(q[r].z, E[4 * r + 2], a2);
            a3 = fmaf(q[r].w, E[4 * r + 3], a3);
        }
        float pn = ((a0 + a1) + (a2 + a3)) * ef;
        pv = (mc[u] > 0) ? pn : pv;
        sp[j] = pv;
    }

    // Final: log(sum_i exp(trans[i][END]) * p[i]) + shift
    float eend = __expf(trans[jc * TT + (TT - 1)]);
    float val = act ? (eend * pv) : 0.0f;
#pragma unroll
    for (int o = 32; o >= 1; o >>= 1)
        val += __shfl_xor(val, o, 64);
    if (j == 0) atomicAdd(out, __logf(val) + shift);
}

extern "C" void kernel_launch(void* const* d_in, const int* in_sizes, int n_in,
                              void* d_out, int out_size, void* d_ws, size_t ws_size,
                              hipStream_t stream) {
    const float* feats = (const float*)d_in[0];
    const int*   mask  = (const int*)d_in[1];
    const float* trans = (const float*)d_in[2];
    float* out = (float*)d_out;

    const int B = in_sizes[1] / LL;   // mask is (B, L)

    hipMemsetAsync(d_out, 0, sizeof(float), stream);
    crf_fwd<<<B, 64, 0, stream>>>(feats, mask, trans, out);
}